// Round 1
// baseline (13106.836 us; speedup 1.0000x reference)
//
#include <hip/hip_runtime.h>
#include <hip/hip_bf16.h>

typedef unsigned short u16;
typedef unsigned int u32;

#define HD 512
#define BATCH 128
#define TENC 512
#define WPAD 520   // LDS row stride in bf16 elems: 520*4B-words%32 spreads banks uniformly

typedef float f32x4 __attribute__((ext_vector_type(4)));
typedef short s16x8 __attribute__((ext_vector_type(8)));

__device__ __forceinline__ u16 f2b(float f) {
    u32 u = __float_as_uint(f);
    u32 r = (u + 0x7FFFu + ((u >> 16) & 1u)) >> 16;   // RNE
    return (u16)r;
}
__device__ __forceinline__ float b2f(u16 h) {
    return __uint_as_float(((u32)h) << 16);
}
__device__ __forceinline__ float sigm(float z) { return 1.0f / (1.0f + __expf(-z)); }
__device__ __forceinline__ float tanh_f(float z) { return 1.0f - 2.0f / (__expf(2.0f * z) + 1.0f); }

// ---------------------------------------------------------------------------
// init: zero group barrier counters, seed h_buf[g][0] from h0 (bf16),
// build rnn_Whh transposed bf16 [k][j] for coalesced decoder reads.
// ---------------------------------------------------------------------------
__global__ void init_misc(const float* __restrict__ h0, const float* __restrict__ rWhh,
                          u16* __restrict__ hbuf, u16* __restrict__ rT,
                          u32* __restrict__ cnt) {
    int idx = blockIdx.x * 256 + threadIdx.x;      // 512 blocks x 256 = 131072
    if (idx < 8) cnt[idx * 64] = 0u;
    if (idx < 65536) {                              // 128*512 h0 values
        int bg = idx >> 9, j = idx & 511;
        int g = bg >> 4, bl = bg & 15;
        hbuf[(size_t)(g * 2) * 8192 + bl * 512 + j] = f2b(h0[idx]);
    }
    for (int i = idx; i < 262144; i += 131072) {    // rT[k*512+j] = rWhh[j][k]
        int k = i >> 9, j = i & 511;
        rT[i] = f2b(rWhh[j * 512 + k]);
    }
}

// ---------------------------------------------------------------------------
// Encoder LSTM: 8 independent batch-groups (16 batch each) x 16 wgs.
// wg (g, sl): batch tile g, hidden slice sl*32..+32 (all 4 gates = 128 rows),
// weights LDS-resident bf16. Per step: stage h -> MFMA -> cell -> barrier(16).
// ---------------------------------------------------------------------------
__global__ __launch_bounds__(512, 2) void enc_lstm(
    const float* __restrict__ xseq, const float* __restrict__ c0,
    const float* __restrict__ Wih, const float* __restrict__ Whh,
    const float* __restrict__ bih, const float* __restrict__ bhh,
    u16* __restrict__ enc, u16* __restrict__ hbuf, u32* __restrict__ cnt) {

    __shared__ u16 wlds[128 * WPAD];    // 133120 B: Whh rows (gate*32+jj) x 512k, bf16
    __shared__ u16 hlds[16 * WPAD];     // 16640 B: staged h tile [16b][512k] bf16
    __shared__ float exg[16 * 132];     // 8448 B: gate pre-activations [b][128 rows]
    __shared__ float bias_l[128];
    __shared__ float wih_l[128];

    const int tid = threadIdx.x;
    const int g = blockIdx.x & 7;       // batch group (XCD-local if round-robin)
    const int sl = blockIdx.x >> 3;     // hidden slot 0..15

    // preload weight slice fp32 -> bf16 LDS (row r = gate*32+jj)
    for (int idx = tid; idx < 128 * 512; idx += 512) {
        int r = idx >> 9, k = idx & 511;
        int grow = (r >> 5) * 512 + sl * 32 + (r & 31);
        wlds[r * WPAD + k] = f2b(Whh[grow * 512 + k]);
    }
    if (tid < 128) {
        int n = (tid >> 5) * 512 + sl * 32 + (tid & 31);
        bias_l[tid] = bih[n] + bhh[n];
        wih_l[tid] = Wih[n];
    }

    const int bT = tid >> 5, jl = tid & 31;               // cell-update mapping (512 thr)
    float c = c0[(g * 16 + bT) * HD + sl * 32 + jl];      // persistent cell state

    const int lane = tid & 63, wv = tid >> 6;
    const int q = lane >> 4, cl = lane & 15;
    const int R = (wv >> 1) * 32 + (wv & 1) * 16;         // wave's 16 gate-rows

    u32* mycnt = &cnt[g * 64];
    __syncthreads();

    for (int t = 0; t < TENC; ++t) {
        // stage h[t&1] -> LDS (16KB, padded rows)
        const uint4* src = (const uint4*)(hbuf + (size_t)(g * 2 + (t & 1)) * 8192);
        for (int cc = tid; cc < 1024; cc += 512) {
            int b = cc >> 6, kq = cc & 63;
            *(uint4*)&hlds[b * WPAD + kq * 8] = src[cc];
        }
        __syncthreads();

        f32x4 acc = {0.f, 0.f, 0.f, 0.f};
        #pragma unroll
        for (int ks = 0; ks < 16; ++ks) {
            s16x8 av = *(const s16x8*)&hlds[cl * WPAD + ks * 32 + q * 8];
            s16x8 bv = *(const s16x8*)&wlds[(R + cl) * WPAD + ks * 32 + q * 8];
            acc = __builtin_amdgcn_mfma_f32_16x16x32_bf16(av, bv, acc, 0, 0, 0);
        }
        #pragma unroll
        for (int r4 = 0; r4 < 4; ++r4)
            exg[(q * 4 + r4) * 132 + R + cl] = acc[r4];   // D: row m=q*4+r4 (batch), col n=cl
        __syncthreads();

        // LSTM cell for (bT, jl)
        const float* exb = &exg[bT * 132];
        float xv = xseq[t * BATCH + g * 16 + bT];
        float gi = exb[jl]      + xv * wih_l[jl]      + bias_l[jl];
        float gf = exb[32 + jl] + xv * wih_l[32 + jl] + bias_l[32 + jl];
        float gg = exb[64 + jl] + xv * wih_l[64 + jl] + bias_l[64 + jl];
        float go = exb[96 + jl] + xv * wih_l[96 + jl] + bias_l[96 + jl];
        c = sigm(gf) * c + sigm(gi) * tanh_f(gg);
        float hv = sigm(go) * tanh_f(c);
        u16 h16 = f2b(hv);
        int jgl = sl * 32 + jl;
        hbuf[(size_t)(g * 2 + ((t + 1) & 1)) * 8192 + bT * HD + jgl] = h16;
        enc[((size_t)t * BATCH + g * 16 + bT) * HD + jgl] = h16;

        __threadfence();              // make h writes device-visible before flag
        __syncthreads();
        if (tid == 0) {
            __hip_atomic_fetch_add(mycnt, 1u, __ATOMIC_RELEASE, __HIP_MEMORY_SCOPE_AGENT);
            u32 tgt = 16u * (u32)(t + 1);
            while (__hip_atomic_load(mycnt, __ATOMIC_ACQUIRE, __HIP_MEMORY_SCOPE_AGENT) < tgt)
                __builtin_amdgcn_s_sleep(1);
        }
        __syncthreads();
    }
}

// ---------------------------------------------------------------------------
// Decoder step (one launch per step): wg per batch row b.
// phase1: h' = tanh(x*Wih + h@Whh^T + b)  (rT streamed from L2, coalesced)
// phase2: online-softmax attention over 512 enc rows (single pass)
// phase3: out = relu(ctx/L . linW + lb)
// ---------------------------------------------------------------------------
__global__ __launch_bounds__(512, 2) void dec_step(
    int s, const float* __restrict__ xprev, const u16* __restrict__ hprev,
    u16* __restrict__ hnext, const u16* __restrict__ enc,
    const u16* __restrict__ rT, const float* __restrict__ rWih,
    const float* __restrict__ rbih, const float* __restrict__ rbhh,
    const float* __restrict__ linW, const float* __restrict__ linb,
    float* __restrict__ dout) {

    __shared__ float hp[512];
    __shared__ float hn[512];
    __shared__ float ctxl[8 * 512];
    __shared__ float red[512];
    __shared__ float mw[8], lw[8];

    const int tid = threadIdx.x;
    const int b = blockIdx.x;

    hp[tid] = b2f(hprev[b * HD + tid]);
    float xb = xprev[b];
    __syncthreads();

    // phase 1: thread per output j
    float a = rbih[tid] + rbhh[tid] + xb * rWih[tid];
    for (int k = 0; k < 512; ++k)
        a = fmaf(hp[k], b2f(rT[k * HD + tid]), a);
    float hv = tanh_f(a);
    hn[tid] = hv;
    hnext[b * HD + tid] = f2b(hv);
    __syncthreads();

    // phase 2: 8 waves, wave wv handles t = tt*8+wv; lane owns j-slice lane*8..+8
    const int wv = tid >> 6, lane = tid & 63;
    float h8[8];
    #pragma unroll
    for (int i = 0; i < 8; ++i) h8[i] = hn[lane * 8 + i];
    float m = -1e30f, l = 0.f;
    float acc[8] = {0, 0, 0, 0, 0, 0, 0, 0};
    for (int tt = 0; tt < 64; ++tt) {
        int t = tt * 8 + wv;
        uint4 ev = *(const uint4*)(enc + ((size_t)(t * BATCH + b)) * HD + lane * 8);
        float e[8];
        e[0] = b2f((u16)(ev.x & 0xFFFF)); e[1] = b2f((u16)(ev.x >> 16));
        e[2] = b2f((u16)(ev.y & 0xFFFF)); e[3] = b2f((u16)(ev.y >> 16));
        e[4] = b2f((u16)(ev.z & 0xFFFF)); e[5] = b2f((u16)(ev.z >> 16));
        e[6] = b2f((u16)(ev.w & 0xFFFF)); e[7] = b2f((u16)(ev.w >> 16));
        float sp = 0.f;
        #pragma unroll
        for (int i = 0; i < 8; ++i) sp = fmaf(e[i], h8[i], sp);
        #pragma unroll
        for (int mk = 1; mk < 64; mk <<= 1) sp += __shfl_xor(sp, mk, 64);
        if (sp > m) {
            float sc = __expf(m - sp);
            l *= sc;
            #pragma unroll
            for (int i = 0; i < 8; ++i) acc[i] *= sc;
            m = sp;
        }
        float p = __expf(sp - m);
        l += p;
        #pragma unroll
        for (int i = 0; i < 8; ++i) acc[i] = fmaf(p, e[i], acc[i]);
    }
    if (lane == 0) { mw[wv] = m; lw[wv] = l; }
    #pragma unroll
    for (int i = 0; i < 8; ++i) ctxl[wv * HD + lane * 8 + i] = acc[i];
    __syncthreads();

    // phase 3: combine 8 waves' online-softmax states, project, relu
    float M = mw[0];
    #pragma unroll
    for (int i = 1; i < 8; ++i) M = fmaxf(M, mw[i]);
    float aw[8]; float L = 0.f;
    #pragma unroll
    for (int i = 0; i < 8; ++i) { aw[i] = __expf(mw[i] - M); L += aw[i] * lw[i]; }
    float cj = 0.f;
    #pragma unroll
    for (int i = 0; i < 8; ++i) cj = fmaf(aw[i], ctxl[i * HD + tid], cj);
    red[tid] = cj * linW[tid];
    __syncthreads();
    for (int st = 256; st > 0; st >>= 1) {
        if (tid < st) red[tid] += red[tid + st];
        __syncthreads();
    }
    if (tid == 0) {
        float o = red[0] / L + linb[0];
        dout[s * BATCH + b] = fmaxf(o, 0.f);
    }
}

// ---------------------------------------------------------------------------
extern "C" void kernel_launch(void* const* d_in, const int* in_sizes, int n_in,
                              void* d_out, int out_size, void* d_ws, size_t ws_size,
                              hipStream_t stream) {
    const float* xseq = (const float*)d_in[0];   // [513,128,1]
    const float* h0   = (const float*)d_in[1];
    const float* c0   = (const float*)d_in[2];
    const float* Wih  = (const float*)d_in[3];   // [2048,1]
    const float* Whh  = (const float*)d_in[4];   // [2048,512]
    const float* bih  = (const float*)d_in[5];
    const float* bhh  = (const float*)d_in[6];
    const float* rWih = (const float*)d_in[7];   // [512,1]
    const float* rWhh = (const float*)d_in[8];   // [512,512]
    const float* rbih = (const float*)d_in[9];
    const float* rbhh = (const float*)d_in[10];
    const float* linW = (const float*)d_in[11];  // [1,512]
    const float* linb = (const float*)d_in[12];
    float* dout = (float*)d_out;                 // [32,128,1]

    // workspace layout (≈68.2 MB)
    char* ws = (char*)d_ws;
    u16* enc  = (u16*)ws;                                      // 512*128*512 bf16 = 64 MB
    u16* rT   = (u16*)(ws + 67108864);                         // 512 KB
    u16* hbuf = (u16*)(ws + 67108864 + 524288);                // 8 groups x 2 x 16 x 512 bf16
    u16* hdec = (u16*)(ws + 67108864 + 524288 + 262144);       // 2 x 128 x 512 bf16
    u32* cnt  = (u32*)(ws + 67108864 + 524288 + 262144 + 262144);

    init_misc<<<512, 256, 0, stream>>>(h0, rWhh, hbuf, rT, cnt);
    enc_lstm<<<128, 512, 0, stream>>>(xseq, c0, Wih, Whh, bih, bhh, enc, hbuf, cnt);

    for (int s = 0; s < 32; ++s) {
        const float* xp  = (s == 0) ? (xseq + 512 * BATCH) : (dout + (s - 1) * BATCH);
        const u16*  hpv  = (s == 0) ? (enc + (size_t)511 * BATCH * HD) : (hdec + (s & 1) * 65536);
        u16*        hnx  = hdec + ((s + 1) & 1) * 65536;
        dec_step<<<128, 512, 0, stream>>>(s, xp, hpv, hnx, enc, rT, rWih,
                                          rbih, rbhh, linW, linb, dout);
    }
}

// Round 2
// 3719.703 us; speedup vs baseline: 3.5236x; 3.5236x over previous
//
#include <hip/hip_runtime.h>
#include <hip/hip_bf16.h>

typedef unsigned short u16;
typedef unsigned int u32;

#define HD 512
#define BATCH 128
#define TENC 512
#define WPAD 520   // LDS row stride in bf16 elems (even -> u32-aligned rows)

typedef float f32x4 __attribute__((ext_vector_type(4)));
typedef short s16x8 __attribute__((ext_vector_type(8)));

__device__ __forceinline__ u16 f2b(float f) {
    u32 u = __float_as_uint(f);
    u32 r = (u + 0x7FFFu + ((u >> 16) & 1u)) >> 16;   // RNE
    return (u16)r;
}
__device__ __forceinline__ float b2f(u16 h) {
    return __uint_as_float(((u32)h) << 16);
}
__device__ __forceinline__ float sigm(float z) { return 1.0f / (1.0f + __expf(-z)); }
__device__ __forceinline__ float tanh_f(float z) { return 1.0f - 2.0f / (__expf(2.0f * z) + 1.0f); }

// ---------------------------------------------------------------------------
// init: zero group barrier counters, seed h_buf[g][0] from h0 (bf16),
// build rnn_Whh transposed bf16 [k][j] for coalesced decoder reads.
// (kernel-boundary flush makes these plain stores visible to sc0/sc1 readers)
// ---------------------------------------------------------------------------
__global__ void init_misc(const float* __restrict__ h0, const float* __restrict__ rWhh,
                          u16* __restrict__ hbuf, u16* __restrict__ rT,
                          u32* __restrict__ cnt) {
    int idx = blockIdx.x * 256 + threadIdx.x;      // 512 blocks x 256 = 131072
    if (idx < 8) cnt[idx * 64] = 0u;
    if (idx < 65536) {                              // 128*512 h0 values
        int bg = idx >> 9, j = idx & 511;
        int g = bg >> 4, bl = bg & 15;
        hbuf[(size_t)(g * 2) * 8192 + bl * 512 + j] = f2b(h0[idx]);
    }
    for (int i = idx; i < 262144; i += 131072) {    // rT[k*512+j] = rWhh[j][k]
        int k = i >> 9, j = i & 511;
        rT[i] = f2b(rWhh[j * 512 + k]);
    }
}

// ---------------------------------------------------------------------------
// Encoder LSTM: 8 independent batch-groups (16 batch each) x 16 wgs.
// Cross-wg h handoff: write-through relaxed-agent atomic u32 stores,
// relaxed-agent atomic flag + relaxed polls (NO bulk wbl2/inv cache ops).
// ---------------------------------------------------------------------------
__global__ __launch_bounds__(512, 2) void enc_lstm(
    const float* __restrict__ xseq, const float* __restrict__ c0,
    const float* __restrict__ Wih, const float* __restrict__ Whh,
    const float* __restrict__ bih, const float* __restrict__ bhh,
    u16* __restrict__ enc, u32* __restrict__ hb32, u32* __restrict__ cnt) {

    __shared__ u16 wlds[128 * WPAD];    // 133120 B: Whh rows (gate*32+jj) x 512k, bf16
    __shared__ u16 hlds[16 * WPAD];     // 16640 B: staged h tile [16b][512k] bf16
    __shared__ float exg[16 * 132];     // 8448 B: gate pre-activations [b][128 rows]
    __shared__ float bias_l[128];
    __shared__ float wih_l[128];

    const int tid = threadIdx.x;
    const int g = blockIdx.x & 7;       // batch group
    const int sl = blockIdx.x >> 3;     // hidden slot 0..15

    // preload weight slice fp32 -> bf16 LDS (row r = gate*32+jj)
    for (int idx = tid; idx < 128 * 512; idx += 512) {
        int r = idx >> 9, k = idx & 511;
        int grow = (r >> 5) * 512 + sl * 32 + (r & 31);
        wlds[r * WPAD + k] = f2b(Whh[grow * 512 + k]);
    }
    if (tid < 128) {
        int n = (tid >> 5) * 512 + sl * 32 + (tid & 31);
        bias_l[tid] = bih[n] + bhh[n];
        wih_l[tid] = Wih[n];
    }

    const int bT = tid >> 5, jl = tid & 31;               // cell-update mapping
    float c = c0[(g * 16 + bT) * HD + sl * 32 + jl];      // persistent cell state

    const int lane = tid & 63, wv = tid >> 6;
    const int q = lane >> 4, cl = lane & 15;
    const int R = (wv >> 1) * 32 + (wv & 1) * 16;         // wave's 16 gate-rows

    u32* mycnt = &cnt[g * 64];
    u32* hlds32 = (u32*)hlds;
    __syncthreads();

    for (int t = 0; t < TENC; ++t) {
        // stage h[t&1] -> LDS via coherent (sc0 sc1) u32 loads
        const u32* src32 = hb32 + (size_t)(g * 2 + (t & 1)) * 4096;
        #pragma unroll
        for (int i = 0; i < 8; ++i) {
            int idx = tid + i * 512;
            u32 v = __hip_atomic_load(src32 + idx, __ATOMIC_RELAXED,
                                      __HIP_MEMORY_SCOPE_AGENT);
            int b = idx >> 8, w = idx & 255;
            hlds32[b * 260 + w] = v;
        }
        __syncthreads();

        f32x4 acc = {0.f, 0.f, 0.f, 0.f};
        #pragma unroll
        for (int ks = 0; ks < 16; ++ks) {
            s16x8 av = *(const s16x8*)&hlds[cl * WPAD + ks * 32 + q * 8];
            s16x8 bv = *(const s16x8*)&wlds[(R + cl) * WPAD + ks * 32 + q * 8];
            acc = __builtin_amdgcn_mfma_f32_16x16x32_bf16(av, bv, acc, 0, 0, 0);
        }
        #pragma unroll
        for (int r4 = 0; r4 < 4; ++r4)
            exg[(q * 4 + r4) * 132 + R + cl] = acc[r4];   // D: row m=q*4+r4, col n=cl
        __syncthreads();

        // LSTM cell for (bT, jl)
        const float* exb = &exg[bT * 132];
        float xv = xseq[t * BATCH + g * 16 + bT];
        float gi = exb[jl]      + xv * wih_l[jl]      + bias_l[jl];
        float gf = exb[32 + jl] + xv * wih_l[32 + jl] + bias_l[32 + jl];
        float gg = exb[64 + jl] + xv * wih_l[64 + jl] + bias_l[64 + jl];
        float go = exb[96 + jl] + xv * wih_l[96 + jl] + bias_l[96 + jl];
        c = sigm(gf) * c + sigm(gi) * tanh_f(gg);
        float hv = sigm(go) * tanh_f(c);
        u16 h16 = f2b(hv);
        int jgl = sl * 32 + jl;

        // pack (jl even, jl odd) -> u32, write-through store (device-visible)
        u32 me = (u32)h16;
        u32 up = (u32)__shfl_down((int)me, 1, 64);
        if ((jl & 1) == 0) {
            u32 pair = me | (up << 16);
            __hip_atomic_store(hb32 + (size_t)(g * 2 + ((t + 1) & 1)) * 4096
                                    + bT * 256 + (jgl >> 1),
                               pair, __ATOMIC_RELAXED, __HIP_MEMORY_SCOPE_AGENT);
        }
        enc[((size_t)t * BATCH + g * 16 + bT) * HD + jgl] = h16;   // plain (next kernel)

        __builtin_amdgcn_s_waitcnt(0);   // per-wave drain of write-through stores
        __syncthreads();                 // all waves drained
        if (tid == 0) {
            __hip_atomic_fetch_add(mycnt, 1u, __ATOMIC_RELAXED, __HIP_MEMORY_SCOPE_AGENT);
            u32 tgt = 16u * (u32)(t + 1);
            while (__hip_atomic_load(mycnt, __ATOMIC_RELAXED, __HIP_MEMORY_SCOPE_AGENT) < tgt)
                __builtin_amdgcn_s_sleep(1);
        }
        __atomic_signal_fence(__ATOMIC_SEQ_CST);
        __syncthreads();
    }
}

// ---------------------------------------------------------------------------
// Decoder step (one launch per step): wg per batch row b.
// phase1: h' = tanh(x*Wih + h@Whh^T + b) — k-loop split across 8 waves
// phase2: online-softmax attention over 512 enc rows (single pass)
// phase3: out = relu(ctx/L . linW + lb)
// ---------------------------------------------------------------------------
__global__ __launch_bounds__(512, 2) void dec_step(
    int s, const float* __restrict__ xprev, const u16* __restrict__ hprev,
    u16* __restrict__ hnext, const u16* __restrict__ enc,
    const u16* __restrict__ rT, const float* __restrict__ rWih,
    const float* __restrict__ rbih, const float* __restrict__ rbhh,
    const float* __restrict__ linW, const float* __restrict__ linb,
    float* __restrict__ dout) {

    __shared__ float hp[512];
    __shared__ float hn[512];
    __shared__ float ctxl[8 * 512];   // phase1 partials, then phase2 ctx partials
    __shared__ float red[512];
    __shared__ float mw[8], lw[8];

    const int tid = threadIdx.x;
    const int b = blockIdx.x;
    const int wv = tid >> 6, lane = tid & 63;

    hp[tid] = b2f(hprev[b * HD + tid]);
    float xb = xprev[b];
    __syncthreads();

    // phase 1: wave wv covers k in [wv*64, wv*64+64); lane covers 4 u32 (8 j) chunks
    {
        const u32* rT32 = (const u32*)rT;
        float pa[8] = {0, 0, 0, 0, 0, 0, 0, 0};
        const u32* base = rT32 + (size_t)(wv * 64) * 256 + lane;
        #pragma unroll 4
        for (int kk = 0; kk < 64; ++kk) {
            float hk = hp[wv * 64 + kk];
            #pragma unroll
            for (int ch = 0; ch < 4; ++ch) {
                u32 w = base[kk * 256 + ch * 64];
                pa[2 * ch]     = fmaf(hk, b2f((u16)(w & 0xFFFF)), pa[2 * ch]);
                pa[2 * ch + 1] = fmaf(hk, b2f((u16)(w >> 16)),    pa[2 * ch + 1]);
            }
        }
        #pragma unroll
        for (int ch = 0; ch < 4; ++ch) {
            ctxl[wv * 512 + ch * 128 + 2 * lane]     = pa[2 * ch];
            ctxl[wv * 512 + ch * 128 + 2 * lane + 1] = pa[2 * ch + 1];
        }
    }
    __syncthreads();
    {
        float a = rbih[tid] + rbhh[tid] + xb * rWih[tid];
        #pragma unroll
        for (int i = 0; i < 8; ++i) a += ctxl[i * 512 + tid];
        float hv = tanh_f(a);
        hn[tid] = hv;
        hnext[b * HD + tid] = f2b(hv);
    }
    __syncthreads();

    // phase 2: wave wv handles t = tt*8+wv; lane owns j-slice lane*8..+8
    float h8[8];
    #pragma unroll
    for (int i = 0; i < 8; ++i) h8[i] = hn[lane * 8 + i];
    float m = -1e30f, l = 0.f;
    float acc[8] = {0, 0, 0, 0, 0, 0, 0, 0};
    for (int tt = 0; tt < 64; ++tt) {
        int t = tt * 8 + wv;
        uint4 ev = *(const uint4*)(enc + ((size_t)(t * BATCH + b)) * HD + lane * 8);
        float e[8];
        e[0] = b2f((u16)(ev.x & 0xFFFF)); e[1] = b2f((u16)(ev.x >> 16));
        e[2] = b2f((u16)(ev.y & 0xFFFF)); e[3] = b2f((u16)(ev.y >> 16));
        e[4] = b2f((u16)(ev.z & 0xFFFF)); e[5] = b2f((u16)(ev.z >> 16));
        e[6] = b2f((u16)(ev.w & 0xFFFF)); e[7] = b2f((u16)(ev.w >> 16));
        float sp = 0.f;
        #pragma unroll
        for (int i = 0; i < 8; ++i) sp = fmaf(e[i], h8[i], sp);
        #pragma unroll
        for (int mk = 1; mk < 64; mk <<= 1) sp += __shfl_xor(sp, mk, 64);
        if (sp > m) {
            float sc = __expf(m - sp);
            l *= sc;
            #pragma unroll
            for (int i = 0; i < 8; ++i) acc[i] *= sc;
            m = sp;
        }
        float p = __expf(sp - m);
        l += p;
        #pragma unroll
        for (int i = 0; i < 8; ++i) acc[i] = fmaf(p, e[i], acc[i]);
    }
    if (lane == 0) { mw[wv] = m; lw[wv] = l; }
    #pragma unroll
    for (int i = 0; i < 8; ++i) ctxl[wv * HD + lane * 8 + i] = acc[i];
    __syncthreads();

    // phase 3: combine 8 waves' online-softmax states, project, relu
    float M = mw[0];
    #pragma unroll
    for (int i = 1; i < 8; ++i) M = fmaxf(M, mw[i]);
    float aw[8]; float L = 0.f;
    #pragma unroll
    for (int i = 0; i < 8; ++i) { aw[i] = __expf(mw[i] - M); L += aw[i] * lw[i]; }
    float cj = 0.f;
    #pragma unroll
    for (int i = 0; i < 8; ++i) cj = fmaf(aw[i], ctxl[i * HD + tid], cj);
    red[tid] = cj * linW[tid];
    __syncthreads();
    for (int st = 256; st > 0; st >>= 1) {
        if (tid < st) red[tid] += red[tid + st];
        __syncthreads();
    }
    if (tid == 0) {
        float o = red[0] / L + linb[0];
        dout[s * BATCH + b] = fmaxf(o, 0.f);
    }
}

// ---------------------------------------------------------------------------
extern "C" void kernel_launch(void* const* d_in, const int* in_sizes, int n_in,
                              void* d_out, int out_size, void* d_ws, size_t ws_size,
                              hipStream_t stream) {
    const float* xseq = (const float*)d_in[0];   // [513,128,1]
    const float* h0   = (const float*)d_in[1];
    const float* c0   = (const float*)d_in[2];
    const float* Wih  = (const float*)d_in[3];   // [2048,1]
    const float* Whh  = (const float*)d_in[4];   // [2048,512]
    const float* bih  = (const float*)d_in[5];
    const float* bhh  = (const float*)d_in[6];
    const float* rWih = (const float*)d_in[7];   // [512,1]
    const float* rWhh = (const float*)d_in[8];   // [512,512]
    const float* rbih = (const float*)d_in[9];
    const float* rbhh = (const float*)d_in[10];
    const float* linW = (const float*)d_in[11];  // [1,512]
    const float* linb = (const float*)d_in[12];
    float* dout = (float*)d_out;                 // [32,128,1]

    // workspace layout (≈68.2 MB)
    char* ws = (char*)d_ws;
    u16* enc  = (u16*)ws;                                      // 512*128*512 bf16 = 64 MB
    u16* rT   = (u16*)(ws + 67108864);                         // 512 KB
    u16* hbuf = (u16*)(ws + 67108864 + 524288);                // 8 groups x 2 x 16 x 512 bf16
    u16* hdec = (u16*)(ws + 67108864 + 524288 + 262144);       // 2 x 128 x 512 bf16
    u32* cnt  = (u32*)(ws + 67108864 + 524288 + 262144 + 262144);

    init_misc<<<512, 256, 0, stream>>>(h0, rWhh, hbuf, rT, cnt);
    enc_lstm<<<128, 512, 0, stream>>>(xseq, c0, Wih, Whh, bih, bhh, enc,
                                      (u32*)hbuf, cnt);

    for (int s = 0; s < 32; ++s) {
        const float* xp  = (s == 0) ? (xseq + 512 * BATCH) : (dout + (s - 1) * BATCH);
        const u16*  hpv  = (s == 0) ? (enc + (size_t)511 * BATCH * HD) : (hdec + (s & 1) * 65536);
        u16*        hnx  = hdec + ((s + 1) & 1) * 65536;
        dec_step<<<128, 512, 0, stream>>>(s, xp, hpv, hnx, enc, rT, rWih,
                                          rbih, rbhh, linW, linb, dout);
    }
}

// Round 3
// 2738.220 us; speedup vs baseline: 4.7866x; 1.3584x over previous
//
#include <hip/hip_runtime.h>
#include <hip/hip_bf16.h>

typedef unsigned short u16;
typedef unsigned int u32;

#define HD 512
#define BATCH 128
#define TENC 512
#define WPAD 520   // LDS row stride in bf16 elems (even -> u32-aligned rows)

typedef float f32x4 __attribute__((ext_vector_type(4)));
typedef short s16x8 __attribute__((ext_vector_type(8)));

__device__ __forceinline__ u16 f2b(float f) {
    u32 u = __float_as_uint(f);
    u32 r = (u + 0x7FFFu + ((u >> 16) & 1u)) >> 16;   // RNE
    return (u16)r;
}
__device__ __forceinline__ float b2f(u16 h) {
    return __uint_as_float(((u32)h) << 16);
}
__device__ __forceinline__ float sigm(float z) { return 1.0f / (1.0f + __expf(-z)); }
__device__ __forceinline__ float tanh_f(float z) { return 1.0f - 2.0f / (__expf(2.0f * z) + 1.0f); }

// ---------------------------------------------------------------------------
// init: zero distributed flags, seed h_buf[g][parity 0] from h0 (bf16),
// build rnn_Whh transposed bf16 [k][j] for coalesced decoder reads.
// ---------------------------------------------------------------------------
__global__ void init_misc(const float* __restrict__ h0, const float* __restrict__ rWhh,
                          u16* __restrict__ hbuf, u16* __restrict__ rT,
                          u32* __restrict__ flags) {
    int idx = blockIdx.x * 256 + threadIdx.x;      // 512 blocks x 256 = 131072
    if (idx < 2048) flags[idx] = 0u;                // 8 groups x 16 slots x 16 u32
    if (idx < 65536) {                              // 128*512 h0 values
        int bg = idx >> 9, j = idx & 511;
        int g = bg >> 4, bl = bg & 15;
        hbuf[(size_t)(g * 2) * 8192 + bl * 512 + j] = f2b(h0[idx]);
    }
    for (int i = idx; i < 262144; i += 131072) {    // rT[k*512+j] = rWhh[j][k]
        int k = i >> 9, j = i & 511;
        rT[i] = f2b(rWhh[j * 512 + k]);
    }
}

// ---------------------------------------------------------------------------
// Encoder LSTM: 8 independent batch-groups (16 batch each) x 16 wgs.
// Whh fragments register-resident (no weight LDS). Cross-wg h handoff:
// write-through relaxed-agent u32 stores + per-wg distributed flag slots
// (stores+parallel polls; no RMW serialization, no bulk cache ops).
// ---------------------------------------------------------------------------
__global__ __launch_bounds__(512, 2) void enc_lstm(
    const float* __restrict__ xseq, const float* __restrict__ c0,
    const float* __restrict__ Wih, const float* __restrict__ Whh,
    const float* __restrict__ bih, const float* __restrict__ bhh,
    u16* __restrict__ enc, u32* __restrict__ hb32, u32* __restrict__ flags) {

    __shared__ u16 hlds[16 * WPAD];     // 16640 B: staged h tile [16b][512k] bf16
    __shared__ float exg[16 * 132];     // 8448 B: gate pre-activations [b][128 rows]
    __shared__ float bias_l[128];
    __shared__ float wih_l[128];

    const int tid = threadIdx.x;
    const int g = blockIdx.x & 7;       // batch group
    const int sl = blockIdx.x >> 3;     // hidden slot 0..15

    if (tid < 128) {
        int n = (tid >> 5) * 512 + sl * 32 + (tid & 31);
        bias_l[tid] = bih[n] + bhh[n];
        wih_l[tid] = Wih[n];
    }

    const int bT = tid >> 5, jl = tid & 31;               // cell-update mapping
    float c = c0[(g * 16 + bT) * HD + sl * 32 + jl];      // persistent cell state

    const int lane = tid & 63, wv = tid >> 6;
    const int q = lane >> 4, cl = lane & 15;
    const int R = (wv >> 1) * 32 + (wv & 1) * 16;         // wave's 16 gate-rows

    // hoist this lane's 16 B-fragments of Whh into registers (64 VGPRs)
    s16x8 bw[16];
    {
        int r = R + cl;
        int grow = (r >> 5) * 512 + sl * 32 + (r & 31);
        const float* wrow = Whh + (size_t)grow * 512;
        #pragma unroll
        for (int ks = 0; ks < 16; ++ks) {
            s16x8 v;
            #pragma unroll
            for (int j = 0; j < 8; ++j)
                v[j] = (short)f2b(wrow[ks * 32 + q * 8 + j]);
            bw[ks] = v;
        }
    }

    u32* flg = flags + g * 256;         // 16 slots, 64B (16 u32) stride
    u32* hlds32 = (u32*)hlds;
    __syncthreads();

    for (int t = 0; t < TENC; ++t) {
        // stage h[t&1] -> LDS via coherent u32 loads
        const u32* src32 = hb32 + (size_t)(g * 2 + (t & 1)) * 4096;
        #pragma unroll
        for (int i = 0; i < 8; ++i) {
            int idx = tid + i * 512;
            u32 v = __hip_atomic_load(src32 + idx, __ATOMIC_RELAXED,
                                      __HIP_MEMORY_SCOPE_AGENT);
            int b = idx >> 8, w = idx & 255;
            hlds32[b * 260 + w] = v;
        }
        float xv = xseq[t * BATCH + g * 16 + bT];   // prefetched; used post-MFMA
        __syncthreads();

        f32x4 acc = {0.f, 0.f, 0.f, 0.f};
        #pragma unroll
        for (int ks = 0; ks < 16; ++ks) {
            s16x8 av = *(const s16x8*)&hlds[cl * WPAD + ks * 32 + q * 8];
            acc = __builtin_amdgcn_mfma_f32_16x16x32_bf16(av, bw[ks], acc, 0, 0, 0);
        }
        #pragma unroll
        for (int r4 = 0; r4 < 4; ++r4)
            exg[(q * 4 + r4) * 132 + R + cl] = acc[r4];   // D: row m=q*4+r4, col n=cl
        __syncthreads();

        // LSTM cell for (bT, jl)
        const float* exb = &exg[bT * 132];
        float gi = exb[jl]      + xv * wih_l[jl]      + bias_l[jl];
        float gf = exb[32 + jl] + xv * wih_l[32 + jl] + bias_l[32 + jl];
        float gg = exb[64 + jl] + xv * wih_l[64 + jl] + bias_l[64 + jl];
        float go = exb[96 + jl] + xv * wih_l[96 + jl] + bias_l[96 + jl];
        c = sigm(gf) * c + sigm(gi) * tanh_f(gg);
        float hv = sigm(go) * tanh_f(c);
        u16 h16 = f2b(hv);
        int jgl = sl * 32 + jl;

        // pack (jl even, jl odd) -> u32, write-through store (device-visible)
        u32 me = (u32)h16;
        u32 up = (u32)__shfl_down((int)me, 1, 64);
        if ((jl & 1) == 0) {
            u32 pair = me | (up << 16);
            __hip_atomic_store(hb32 + (size_t)(g * 2 + ((t + 1) & 1)) * 4096
                                    + bT * 256 + (jgl >> 1),
                               pair, __ATOMIC_RELAXED, __HIP_MEMORY_SCOPE_AGENT);
        }

        __builtin_amdgcn_s_waitcnt(0);   // drain h stores to coherence point
        __syncthreads();                 // all waves drained
        if (tid == 0)
            __hip_atomic_store(&flg[sl * 16], (u32)(t + 1),
                               __ATOMIC_RELAXED, __HIP_MEMORY_SCOPE_AGENT);
        // enc write AFTER signal: off the critical drain path
        enc[((size_t)t * BATCH + g * 16 + bT) * HD + jgl] = h16;
        if (tid < 16) {
            while (__hip_atomic_load(&flg[tid * 16], __ATOMIC_RELAXED,
                                     __HIP_MEMORY_SCOPE_AGENT) < (u32)(t + 1))
                __builtin_amdgcn_s_sleep(1);
        }
        __atomic_signal_fence(__ATOMIC_SEQ_CST);
        __syncthreads();
    }
}

// ---------------------------------------------------------------------------
// Fused decoder: batch rows are fully independent -> one wg per b runs all
// 32 steps. p1: h'=tanh(xWih + h@Whh^T + b) (uint4 rT stream, k split over
// 8 waves). p2: online-softmax attention, 4-deep register prefetch of enc.
// p3: out = relu(ctx/L . linW + lb); out feeds next step's x.
// ---------------------------------------------------------------------------
__global__ __launch_bounds__(512, 2) void dec_all(
    const float* __restrict__ xlast, const u16* __restrict__ enc,
    const u16* __restrict__ rT, const float* __restrict__ rWih,
    const float* __restrict__ rbih, const float* __restrict__ rbhh,
    const float* __restrict__ linW, const float* __restrict__ linb,
    float* __restrict__ dout) {

    __shared__ float hp[512];          // h entering the step
    __shared__ float ctxl[8 * 512];    // p1 partials, then p2 ctx partials
    __shared__ float red[512];         // hn broadcast, then reduce slots
    __shared__ float mw[8], lw[8];
    __shared__ float xsh;

    const int tid = threadIdx.x;
    const int b = blockIdx.x;
    const int wv = tid >> 6, lane = tid & 63;

    hp[tid] = b2f(enc[(size_t)511 * BATCH * HD + b * HD + tid]);  // h_enc
    float x = xlast[b];
    const float bia = rbih[tid] + rbhh[tid];
    const float wih = rWih[tid];
    const float lwt = linW[tid];
    const float lb = linb[0];
    const uint4* rT4 = (const uint4*)rT;                 // [512 k][64 chunks]
    const u16* ebase = enc + (size_t)b * HD + lane * 8;  // t-stride = 65536 elems
    __syncthreads();

    for (int s = 0; s < 32; ++s) {
        // issue p2's first prefetch block early (hides IF$ latency under p1)
        uint4 buf[4];
        #pragma unroll
        for (int i = 0; i < 4; ++i)
            buf[i] = *(const uint4*)(ebase + (size_t)(i * 8 + wv) * 65536);

        // ---- phase 1: wave wv covers k in [wv*64, wv*64+64)
        float pa[8] = {0, 0, 0, 0, 0, 0, 0, 0};
        const uint4* base = rT4 + (size_t)(wv * 64) * 64 + lane;
        #pragma unroll 4
        for (int kk = 0; kk < 64; ++kk) {
            float hk = hp[wv * 64 + kk];
            uint4 w = base[kk * 64];
            pa[0] = fmaf(hk, b2f((u16)(w.x & 0xFFFF)), pa[0]);
            pa[1] = fmaf(hk, b2f((u16)(w.x >> 16)),    pa[1]);
            pa[2] = fmaf(hk, b2f((u16)(w.y & 0xFFFF)), pa[2]);
            pa[3] = fmaf(hk, b2f((u16)(w.y >> 16)),    pa[3]);
            pa[4] = fmaf(hk, b2f((u16)(w.z & 0xFFFF)), pa[4]);
            pa[5] = fmaf(hk, b2f((u16)(w.z >> 16)),    pa[5]);
            pa[6] = fmaf(hk, b2f((u16)(w.w & 0xFFFF)), pa[6]);
            pa[7] = fmaf(hk, b2f((u16)(w.w >> 16)),    pa[7]);
        }
        #pragma unroll
        for (int i = 0; i < 8; ++i) ctxl[wv * 512 + lane * 8 + i] = pa[i];
        __syncthreads();

        float a = bia + x * wih;
        #pragma unroll
        for (int i = 0; i < 8; ++i) a += ctxl[i * 512 + tid];
        float hv = tanh_f(a);
        red[tid] = hv;                  // hn broadcast
        __syncthreads();

        // ---- phase 2: wave wv handles t = tt*8+wv, 4-deep prefetch
        float h8[8];
        #pragma unroll
        for (int i = 0; i < 8; ++i) h8[i] = red[lane * 8 + i];
        float m = -1e30f, l = 0.f;
        float acc[8] = {0, 0, 0, 0, 0, 0, 0, 0};
        for (int blk = 0; blk < 16; ++blk) {
            uint4 nxt[4];
            if (blk < 15) {
                #pragma unroll
                for (int i = 0; i < 4; ++i)
                    nxt[i] = *(const uint4*)(ebase +
                               (size_t)((blk + 1) * 32 + i * 8 + wv) * 65536);
            }
            #pragma unroll
            for (int i = 0; i < 4; ++i) {
                uint4 ev = buf[i];
                float e[8];
                e[0] = b2f((u16)(ev.x & 0xFFFF)); e[1] = b2f((u16)(ev.x >> 16));
                e[2] = b2f((u16)(ev.y & 0xFFFF)); e[3] = b2f((u16)(ev.y >> 16));
                e[4] = b2f((u16)(ev.z & 0xFFFF)); e[5] = b2f((u16)(ev.z >> 16));
                e[6] = b2f((u16)(ev.w & 0xFFFF)); e[7] = b2f((u16)(ev.w >> 16));
                float sp = 0.f;
                #pragma unroll
                for (int j = 0; j < 8; ++j) sp = fmaf(e[j], h8[j], sp);
                #pragma unroll
                for (int mk = 1; mk < 64; mk <<= 1) sp += __shfl_xor(sp, mk, 64);
                if (sp > m) {
                    float sc = __expf(m - sp);
                    l *= sc;
                    #pragma unroll
                    for (int j = 0; j < 8; ++j) acc[j] *= sc;
                    m = sp;
                }
                float p = __expf(sp - m);
                l += p;
                #pragma unroll
                for (int j = 0; j < 8; ++j) acc[j] = fmaf(p, e[j], acc[j]);
            }
            #pragma unroll
            for (int i = 0; i < 4; ++i) buf[i] = nxt[i];
        }
        if (lane == 0) { mw[wv] = m; lw[wv] = l; }
        #pragma unroll
        for (int i = 0; i < 8; ++i) ctxl[wv * HD + lane * 8 + i] = acc[i];
        __syncthreads();

        // ---- phase 3: merge online-softmax states, project, relu
        float M = mw[0];
        #pragma unroll
        for (int i = 1; i < 8; ++i) M = fmaxf(M, mw[i]);
        float L = 0.f, aw[8];
        #pragma unroll
        for (int i = 0; i < 8; ++i) { aw[i] = __expf(mw[i] - M); L += aw[i] * lw[i]; }
        float cj = 0.f;
        #pragma unroll
        for (int i = 0; i < 8; ++i) cj = fmaf(aw[i], ctxl[i * HD + tid], cj);
        float r = cj * lwt;
        #pragma unroll
        for (int mk = 1; mk < 64; mk <<= 1) r += __shfl_xor(r, mk, 64);
        if (lane == 0) red[wv] = r;
        __syncthreads();
        if (tid == 0) {
            float o = (red[0] + red[1] + red[2] + red[3] +
                       red[4] + red[5] + red[6] + red[7]) / L + lb;
            o = fmaxf(o, 0.f);
            dout[s * BATCH + b] = o;
            xsh = o;
        }
        __syncthreads();
        x = xsh;
        hp[tid] = hv;                   // h for next step
        __syncthreads();
    }
}

// ---------------------------------------------------------------------------
extern "C" void kernel_launch(void* const* d_in, const int* in_sizes, int n_in,
                              void* d_out, int out_size, void* d_ws, size_t ws_size,
                              hipStream_t stream) {
    const float* xseq = (const float*)d_in[0];   // [513,128,1]
    const float* h0   = (const float*)d_in[1];
    const float* c0   = (const float*)d_in[2];
    const float* Wih  = (const float*)d_in[3];   // [2048,1]
    const float* Whh  = (const float*)d_in[4];   // [2048,512]
    const float* bih  = (const float*)d_in[5];
    const float* bhh  = (const float*)d_in[6];
    const float* rWih = (const float*)d_in[7];   // [512,1]
    const float* rWhh = (const float*)d_in[8];   // [512,512]
    const float* rbih = (const float*)d_in[9];
    const float* rbhh = (const float*)d_in[10];
    const float* linW = (const float*)d_in[11];  // [1,512]
    const float* linb = (const float*)d_in[12];
    float* dout = (float*)d_out;                 // [32,128,1]

    // workspace layout
    char* ws = (char*)d_ws;
    u16* enc   = (u16*)ws;                                     // 64 MB
    u16* rT    = (u16*)(ws + 67108864);                        // 512 KB
    u16* hbuf  = (u16*)(ws + 67108864 + 524288);               // 256 KB
    u32* flags = (u32*)(ws + 67108864 + 524288 + 262144);      // 8 KB

    init_misc<<<512, 256, 0, stream>>>(h0, rWhh, hbuf, rT, flags);
    enc_lstm<<<128, 512, 0, stream>>>(xseq, c0, Wih, Whh, bih, bhh, enc,
                                      (u32*)hbuf, flags);
    dec_all<<<128, 512, 0, stream>>>(xseq + 512 * BATCH, enc, rT, rWih,
                                     rbih, rbhh, linW, linb, dout);
}